// Round 6
// baseline (182.923 us; speedup 1.0000x reference)
//
#include <hip/hip_runtime.h>
#include <stdint.h>

typedef unsigned short u16;
typedef unsigned int   u32;
typedef float   f32x4  __attribute__((ext_vector_type(4)));
typedef float   f32x16 __attribute__((ext_vector_type(16)));
typedef __bf16  bf16x8 __attribute__((ext_vector_type(8)));
typedef u32     u32x4  __attribute__((ext_vector_type(4)));
typedef u32     u32x2  __attribute__((ext_vector_type(2)));

union BF8 { bf16x8 v; u16 s[8]; u32x4 q; };

__device__ __forceinline__ u16 f2b_rne(float f) {
    u32 u = __builtin_bit_cast(u32, f);
    u32 r = u + 0x7FFFu + ((u >> 16) & 1u);
    return (u16)(r >> 16);
}
__device__ __forceinline__ u16 f2b_trunc(float f) {
    return (u16)(__builtin_bit_cast(u32, f) >> 16);
}
__device__ __forceinline__ float b2f(u16 h) {
    u32 u = ((u32)h) << 16;
    return __builtin_bit_cast(float, u);
}
__device__ __forceinline__ bf16x8 ld_bf8(const u16* p) {
    BF8 t; t.q = *(const u32x4*)p; return t.v;
}
__device__ __forceinline__ f32x16 zero16() {
    f32x16 z;
#pragma unroll
    for (int i = 0; i < 16; i++) z[i] = 0.f;
    return z;
}
__device__ __forceinline__ f32x4 zero4() {
    f32x4 z;
#pragma unroll
    for (int i = 0; i < 4; i++) z[i] = 0.f;
    return z;
}

#define SCALE2 0.1275312959479341f        /* log2(e)/sqrt(128) */
#define MBIAS2 -1442.6950408889634f       /* -1000*log2(e) */

// ---------------------------------------------------------------------------
// xt: LDS-tiled transpose.  blocks 0..511: x[8192][128] f32 -> XTh/XTl
// [128][8192] bf16 hi/lo.  blocks 512..519: lw[128][128] f32 -> lwT[128][128]
// bf16 (transposed).  All global reads/writes lane-contiguous.
// ---------------------------------------------------------------------------
__global__ __launch_bounds__(256) void xt_kernel(
    const float* __restrict__ x, const float* __restrict__ lw,
    u16* XTh, u16* XTl, u16* lwT)
{
    __shared__ float xs[32][65];
    int t = threadIdx.x;
    if (blockIdx.x < 512) {
        int ts = blockIdx.x & 127, td = blockIdx.x >> 7;
        int r0 = ts * 64, d0 = td * 32;
        int ci = t & 31, ro = t >> 5;
#pragma unroll
        for (int j = 0; j < 8; j++)
            xs[ci][ro + 8 * j] = x[(size_t)(r0 + ro + 8 * j) * 128 + d0 + ci];
        __syncthreads();
        int ri = t & 63, dj = t >> 6;
#pragma unroll
        for (int jj = 0; jj < 8; jj++) {
            int di = dj + 4 * jj;
            float v = xs[di][ri];
            u16 hi = f2b_trunc(v);
            XTh[(size_t)(d0 + di) * 8192 + r0 + ri] = hi;
            XTl[(size_t)(d0 + di) * 8192 + r0 + ri] = f2b_trunc(v - b2f(hi));
        }
    } else {
        int tb = blockIdx.x - 512;
        int to = (tb & 1) * 64, ti = (tb >> 1) * 32;
        int ci = t & 31, ro = t >> 5;
#pragma unroll
        for (int j = 0; j < 8; j++)
            xs[ci][ro + 8 * j] = lw[(size_t)(to + ro + 8 * j) * 128 + ti + ci];
        __syncthreads();
        int oi = t & 63, dj = t >> 6;
#pragma unroll
        for (int jj = 0; jj < 8; jj++) {
            int ii = dj + 4 * jj;
            lwT[(size_t)(ti + ii) * 128 + to + oi] = f2b_rne(xs[ii][oi]);
        }
    }
}

// ---------------------------------------------------------------------------
// projection: A-frags from XTh/XTl (coalesced), W columns read coalesced and
// split in-reg. Q/K written hi/lo head-packed [b][h][s][16] (Q pre-scaled by
// log2e/sqrt(128)); V written transposed VT[b*128+n][s]. grid (256,3) x 256.
// ---------------------------------------------------------------------------
__global__ __launch_bounds__(256) void proj_kernel(
    const u16* __restrict__ XTh, const u16* __restrict__ XTl,
    const float* __restrict__ wq, const float* __restrict__ wk,
    const float* __restrict__ wv,
    u16* Qph, u16* Qpl, u16* Kph, u16* Kpl, u16* VT)
{
    int typ  = blockIdx.y;                 // 0=Q 1=K 2=V
    int ct   = threadIdx.x >> 6;
    int lane = threadIdx.x & 63;
    int m = lane & 31, kg = lane >> 5;
    int r0 = blockIdx.x * 32;
    int c = ct * 32 + m;

    const float* wp = (typ == 0) ? wq : (typ == 1) ? wk : wv;

    f32x16 acc = zero16();
#pragma unroll 4
    for (int kk = 0; kk < 128; kk += 16) {
        const u16* xh = XTh + (size_t)(kk + kg * 8) * 8192 + r0 + m;
        BF8 ah;
#pragma unroll
        for (int j = 0; j < 8; j++) ah.s[j] = xh[(size_t)j * 8192];
        const float* wcol = wp + (size_t)(kk + kg * 8) * 128 + c;
        if (typ < 2) {
            const u16* xl = XTl + (size_t)(kk + kg * 8) * 8192 + r0 + m;
            BF8 al;
#pragma unroll
            for (int j = 0; j < 8; j++) al.s[j] = xl[(size_t)j * 8192];
            BF8 bh, bl_;
#pragma unroll
            for (int j = 0; j < 8; j++) {
                float w = wcol[(size_t)j * 128];
                u16 hb = f2b_trunc(w);
                bh.s[j] = hb; bl_.s[j] = f2b_trunc(w - b2f(hb));
            }
            acc = __builtin_amdgcn_mfma_f32_32x32x16_bf16(ah.v, bh.v, acc, 0, 0, 0);
            acc = __builtin_amdgcn_mfma_f32_32x32x16_bf16(ah.v, bl_.v, acc, 0, 0, 0);
            acc = __builtin_amdgcn_mfma_f32_32x32x16_bf16(al.v, bh.v, acc, 0, 0, 0);
        } else {
            BF8 bh;
#pragma unroll
            for (int j = 0; j < 8; j++) bh.s[j] = f2b_rne(wcol[(size_t)j * 128]);
            acc = __builtin_amdgcn_mfma_f32_32x32x16_bf16(ah.v, bh.v, acc, 0, 0, 0);
        }
    }

    int b = r0 >> 11, sl = r0 & 2047;
    if (typ < 2) {
        u16* H = typ ? Kph : Qph;
        u16* L = typ ? Kpl : Qpl;
        int hh = c >> 4, d = c & 15;
        if (hh == 7) return;                      // head 7 never consumed
        float scl = (typ == 0) ? SCALE2 : 1.0f;
        size_t hb_off = (size_t)(b * 8 + hh) * 2048 * 16 + d;
#pragma unroll
        for (int r = 0; r < 16; r++) {
            int row = (r & 3) + 8 * (r >> 2) + 4 * kg;
            float v = acc[r] * scl;
            u16 hi = f2b_trunc(v);
            size_t idx = hb_off + (size_t)(sl + row) * 16;
            H[idx] = hi;
            L[idx] = f2b_trunc(v - b2f(hi));
        }
    } else {
        if ((c >> 4) == 7) return;
#pragma unroll
        for (int rg = 0; rg < 4; rg++) {
            int rowb = rg * 8 + 4 * kg;
            BF8 pk;
#pragma unroll
            for (int q = 0; q < 4; q++) pk.s[q] = f2b_rne(acc[rg * 4 + q]);
            u32x4 tmp = pk.q;
            *(u32*)(VT + (size_t)(b * 128 + c) * 2048 + sl + rowb)     = tmp[0];
            *(u32*)(VT + (size_t)(b * 128 + c) * 2048 + sl + rowb + 2) = tmp[1];
        }
    }
}

// ---------------------------------------------------------------------------
// fused attention: round-4 exact two-pass numerics (pass1 = Khi*Qhi + biasC,
// MFMA-accurate to ~1 log2 unit), plus K-prefetch in both passes, pbuf
// stride 34 (odd word stride -> near-conflict-free), 7 blocks/CU resident.
// Epilogue writes AOT[128][8192] (transposed) so fin reads coalesced.
// ---------------------------------------------------------------------------
__global__ __launch_bounds__(256, 7) void attn_kernel(
    const u16* __restrict__ Qph, const u16* __restrict__ Qpl,
    const u16* __restrict__ Kph, const u16* __restrict__ Kpl,
    const u16* __restrict__ VT, const int* __restrict__ mask, u16* AOT)
{
    __shared__ char smem[17408];
    u16*   pbuf  = (u16*)smem;               // [4][32][34] u16 = 8704 B
    float* biasC = (float*)(smem + 8704);    // [64 tiles][2 kg][16 reg] = 8192 B
    float* lsmax = (float*)(smem + 16896);   // [32][4] = 512 B
    float* obuf  = (float*)smem;             // [4][16][32] f32, aliases pbuf
    float* lbuf  = (float*)(smem + 8192);    // [4][32] f32, aliases pbuf tail

    int bid = blockIdx.x;
    int bh = bid % 28;
    int qt = bid / 28;
    int b = bh / 7, h = bh % 7;
    int wave = threadIdx.x >> 6, lane = threadIdx.x & 63;
    int m = lane & 31, kg = lane >> 5;
    int qs = qt * 32;

    // ---- bias table in MFMA C-layout: entry e=(tile*32+kg*16+r)
    //      -> key tile*32 + (r&3)+8*(r>>2)+4*kg ----
    {
        int e0 = threadIdx.x * 8;
        const int* mp = mask + b * 2048;
        float v[8];
#pragma unroll
        for (int j = 0; j < 8; j++) {
            int e = e0 + j;
            int ti = e >> 5, kgg = (e >> 4) & 1, r = e & 15;
            int key = ti * 32 + (r & 3) + 8 * (r >> 2) + 4 * kgg;
            v[j] = (mp[key] != 0) ? 0.0f : MBIAS2;
        }
        *(f32x4*)(biasC + e0)     = *(const f32x4*)&v[0];
        *(f32x4*)(biasC + e0 + 4) = *(const f32x4*)&v[4];
    }
    __syncthreads();

    size_t headoff = (size_t)(b * 8 + h) * 2048 * 16;
    bf16x8 qfh = ld_bf8(Qph + headoff + (size_t)(qs + m) * 16 + kg * 8);
    bf16x8 qfl = ld_bf8(Qpl + headoff + (size_t)(qs + m) * 16 + kg * 8);
    const u16* kbh = Kph + headoff;
    const u16* kbl = Kpl + headoff;

    int t0 = wave * 512;

    // ---- pass 1: per-query max of approx biased scores (K hi x Q hi + bias) ----
    float mloc = -3.0e38f;
    {
        bf16x8 khc = ld_bf8(kbh + (size_t)(t0 + m) * 16 + kg * 8);
        for (int t = t0; t < t0 + 512; t += 32) {
            int tn = (t + 32 < t0 + 512) ? (t + 32) : t0;
            bf16x8 khn = ld_bf8(kbh + (size_t)(tn + m) * 16 + kg * 8);
            f32x16 ci = *(const f32x16*)(biasC + (t >> 5) * 32 + kg * 16);
            f32x16 sc = __builtin_amdgcn_mfma_f32_32x32x16_bf16(khc, qfh, ci, 0, 0, 0);
#pragma unroll
            for (int r = 0; r < 16; r++) mloc = fmaxf(mloc, sc[r]);
            khc = khn;
        }
    }
    mloc = fmaxf(mloc, __shfl_xor(mloc, 32, 64));
    if (kg == 0) lsmax[m * 4 + wave] = mloc;
    __syncthreads();
    f32x4 mv = *(const f32x4*)(lsmax + m * 4);
    float mrow = fmaxf(fmaxf(mv[0], mv[1]), fmaxf(mv[2], mv[3]));  // per-lane (query m)

    // ---- pass 2: exact biased scores -> exp2 -> P tile -> PV + ones-sum ----
    f32x4 o0 = zero4(), o1 = zero4(), l0 = zero4(), l1 = zero4();
    BF8 onesu;
#pragma unroll
    for (int j = 0; j < 8; j++) onesu.s[j] = 0x3F80;
    bf16x8 ones = onesu.v;

    int q16 = lane & 15, krow = lane >> 4;
    const u16* vtb = VT + (size_t)(b * 128 + h * 16 + q16) * 2048;
    u16* pw = pbuf + wave * 1088 + m * 34 + kg * 4;
    const u16* pr0 = pbuf + wave * 1088 + q16 * 34 + krow * 8;
    const u16* pr1 = pr0 + 16 * 34;

    bf16x8 khc = ld_bf8(kbh + (size_t)(t0 + m) * 16 + kg * 8);
    bf16x8 klc = ld_bf8(kbl + (size_t)(t0 + m) * 16 + kg * 8);

    for (int t = t0; t < t0 + 512; t += 32) {
        int tn = (t + 32 < t0 + 512) ? (t + 32) : t0;
        bf16x8 khn = ld_bf8(kbh + (size_t)(tn + m) * 16 + kg * 8);
        bf16x8 kln = ld_bf8(kbl + (size_t)(tn + m) * 16 + kg * 8);
        bf16x8 vf  = ld_bf8(vtb + t + krow * 8);

        f32x16 sc = *(const f32x16*)(biasC + (t >> 5) * 32 + kg * 16);
        sc = __builtin_amdgcn_mfma_f32_32x32x16_bf16(khc, qfl, sc, 0, 0, 0);
        sc = __builtin_amdgcn_mfma_f32_32x32x16_bf16(klc, qfh, sc, 0, 0, 0);
        sc = __builtin_amdgcn_mfma_f32_32x32x16_bf16(khc, qfh, sc, 0, 0, 0);
#pragma unroll
        for (int rg = 0; rg < 4; rg++) {
            float e0 = __builtin_amdgcn_exp2f(sc[rg * 4 + 0] - mrow);
            float e1 = __builtin_amdgcn_exp2f(sc[rg * 4 + 1] - mrow);
            float e2 = __builtin_amdgcn_exp2f(sc[rg * 4 + 2] - mrow);
            float e3 = __builtin_amdgcn_exp2f(sc[rg * 4 + 3] - mrow);
            u32x2 pk;
            pk[0] = __builtin_amdgcn_perm(__builtin_bit_cast(u32, e1),
                                          __builtin_bit_cast(u32, e0), 0x07060302u);
            pk[1] = __builtin_amdgcn_perm(__builtin_bit_cast(u32, e3),
                                          __builtin_bit_cast(u32, e2), 0x07060302u);
            *(u32x2*)(pw + rg * 8) = pk;     // keys rg*8+4kg..+3 for query m
        }
        bf16x8 p0 = *(const bf16x8*)pr0;
        bf16x8 p1 = *(const bf16x8*)pr1;
        o0 = __builtin_amdgcn_mfma_f32_16x16x32_bf16(p0, vf, o0, 0, 0, 0);
        o1 = __builtin_amdgcn_mfma_f32_16x16x32_bf16(p1, vf, o1, 0, 0, 0);
        l0 = __builtin_amdgcn_mfma_f32_16x16x32_bf16(p0, ones, l0, 0, 0, 0);
        l1 = __builtin_amdgcn_mfma_f32_16x16x32_bf16(p1, ones, l1, 0, 0, 0);
        khc = khn; klc = kln;
    }

    __syncthreads();     // all P-tile reads done before obuf/lbuf alias writes

    *(f32x4*)(obuf + wave * 512 + q16 * 32 + krow * 4)      = o0;
    *(f32x4*)(obuf + wave * 512 + q16 * 32 + krow * 4 + 16) = o1;
    if (q16 == 0) {
        *(f32x4*)(lbuf + wave * 32 + krow * 4)      = l0;
        *(f32x4*)(lbuf + wave * 32 + krow * 4 + 16) = l1;
    }
    __syncthreads();

    int dd = threadIdx.x & 15, q = threadIdx.x >> 4;
    int slot0 = (h == 0) ? 0 : h + 1;
#pragma unroll
    for (int hf = 0; hf < 2; hf++) {
        int qq = q + hf * 16;
        float os = obuf[0 * 512 + dd * 32 + qq] + obuf[1 * 512 + dd * 32 + qq]
                 + obuf[2 * 512 + dd * 32 + qq] + obuf[3 * 512 + dd * 32 + qq];
        float ls = lbuf[0 * 32 + qq] + lbuf[1 * 32 + qq]
                 + lbuf[2 * 32 + qq] + lbuf[3 * 32 + qq];
        u16 vb = f2b_rne(os * __builtin_amdgcn_rcpf(ls));
        int orow = b * 2048 + qs + qq;
        AOT[(size_t)(slot0 * 16 + dd) * 8192 + orow] = vb;
        if (h == 1) AOT[(size_t)(16 + dd) * 8192 + orow] = vb;
    }
}

// ---------------------------------------------------------------------------
// final linear: out = AO @ lin_w^T + lin_b.  A from AOT (coalesced), B from
// lwT (coalesced).  grid 256 x 256.
// ---------------------------------------------------------------------------
__global__ __launch_bounds__(256) void fin_kernel(
    const u16* __restrict__ AOT, const u16* __restrict__ lwT,
    const float* __restrict__ lb, float* out)
{
    int ct   = threadIdx.x >> 6;
    int lane = threadIdx.x & 63;
    int m = lane & 31, kg = lane >> 5;
    int r0 = blockIdx.x * 32;
    int c = ct * 32 + m;

    f32x16 acc = zero16();
#pragma unroll 4
    for (int kk = 0; kk < 128; kk += 16) {
        BF8 af, bfr;
        const u16* ap = AOT + (size_t)(kk + kg * 8) * 8192 + r0 + m;
        const u16* bp = lwT + (size_t)(kk + kg * 8) * 128 + c;
#pragma unroll
        for (int j = 0; j < 8; j++) {
            af.s[j]  = ap[(size_t)j * 8192];
            bfr.s[j] = bp[(size_t)j * 128];
        }
        acc = __builtin_amdgcn_mfma_f32_32x32x16_bf16(af.v, bfr.v, acc, 0, 0, 0);
    }
    float bias = lb[c];
#pragma unroll
    for (int r = 0; r < 16; r++) {
        int row = (r & 3) + 8 * (r >> 2) + 4 * kg;
        out[(size_t)(r0 + row) * 128 + c] = acc[r] + bias;
    }
}

// ---------------------------------------------------------------------------
extern "C" void kernel_launch(void* const* d_in, const int* in_sizes, int n_in,
                              void* d_out, int out_size, void* d_ws, size_t ws_size,
                              hipStream_t stream)
{
    const float* x    = (const float*)d_in[0];
    const int*   mask = (const int*)d_in[1];
    const float* wq   = (const float*)d_in[2];
    const float* wk   = (const float*)d_in[3];
    const float* wv   = (const float*)d_in[4];
    const float* lw   = (const float*)d_in[5];
    const float* lb   = (const float*)d_in[6];
    float* out = (float*)d_out;

    char* ws = (char*)d_ws;
    u16* XTh = (u16*)(ws + 0 * 2097152);   // reused as AOT after proj is done
    u16* XTl = (u16*)(ws + 1 * 2097152);
    u16* Qph = (u16*)(ws + 2 * 2097152);
    u16* Qpl = (u16*)(ws + 3 * 2097152);
    u16* Kph = (u16*)(ws + 4 * 2097152);
    u16* Kpl = (u16*)(ws + 5 * 2097152);
    u16* VT  = (u16*)(ws + 6 * 2097152);
    u16* lwT = (u16*)(ws + 7 * 2097152);
    u16* AOT = XTh;                        // alias: XTh dead after proj_kernel

    xt_kernel<<<520, 256, 0, stream>>>(x, lw, XTh, XTl, lwT);
    proj_kernel<<<dim3(256, 3), 256, 0, stream>>>(XTh, XTl, wq, wk, wv,
                                                  Qph, Qpl, Kph, Kpl, VT);
    attn_kernel<<<1792, 256, 0, stream>>>(Qph, Qpl, Kph, Kpl, VT, mask, AOT);
    fin_kernel<<<256, 256, 0, stream>>>(AOT, lwT, lb, out);
}

// Round 7
// 121.395 us; speedup vs baseline: 1.5068x; 1.5068x over previous
//
#include <hip/hip_runtime.h>
#include <stdint.h>

typedef unsigned short u16;
typedef unsigned int   u32;
typedef float   f32x4  __attribute__((ext_vector_type(4)));
typedef float   f32x16 __attribute__((ext_vector_type(16)));
typedef __bf16  bf16x8 __attribute__((ext_vector_type(8)));
typedef u32     u32x4  __attribute__((ext_vector_type(4)));
typedef u32     u32x2  __attribute__((ext_vector_type(2)));

union BF8 { bf16x8 v; u16 s[8]; u32x4 q; };

__device__ __forceinline__ u16 f2b_rne(float f) {
    u32 u = __builtin_bit_cast(u32, f);
    u32 r = u + 0x7FFFu + ((u >> 16) & 1u);
    return (u16)(r >> 16);
}
__device__ __forceinline__ u16 f2b_trunc(float f) {
    return (u16)(__builtin_bit_cast(u32, f) >> 16);
}
__device__ __forceinline__ float b2f(u16 h) {
    u32 u = ((u32)h) << 16;
    return __builtin_bit_cast(float, u);
}
__device__ __forceinline__ bf16x8 ld_bf8(const u16* p) {
    BF8 t; t.q = *(const u32x4*)p; return t.v;
}
__device__ __forceinline__ f32x16 zero16() {
    f32x16 z;
#pragma unroll
    for (int i = 0; i < 16; i++) z[i] = 0.f;
    return z;
}
__device__ __forceinline__ f32x4 zero4() {
    f32x4 z;
#pragma unroll
    for (int i = 0; i < 4; i++) z[i] = 0.f;
    return z;
}

#define SCALE2 0.1275312959479341f        /* log2(e)/sqrt(128) */
#define MBIAS2 -1442.6950408889634f       /* -1000*log2(e) */

// ---------------------------------------------------------------------------
// projection: W columns read coalesced (lane-consecutive c) and hi/lo split
// in-reg. Q/K written hi/lo head-packed [b][h][s][16] (Q pre-scaled by
// log2e/sqrt(128)); V written transposed VT[b*128+n][s]. grid (256,3) x 256.
// ---------------------------------------------------------------------------
__global__ __launch_bounds__(256) void proj_kernel(
    const float* __restrict__ x, const float* __restrict__ wq,
    const float* __restrict__ wk, const float* __restrict__ wv,
    u16* Qph, u16* Qpl, u16* Kph, u16* Kpl, u16* VT)
{
    int typ  = blockIdx.y;                 // 0=Q 1=K 2=V
    int ct   = threadIdx.x >> 6;
    int lane = threadIdx.x & 63;
    int m = lane & 31, kg = lane >> 5;
    int r0 = blockIdx.x * 32;
    int c = ct * 32 + m;

    const float* wp = (typ == 0) ? wq : (typ == 1) ? wk : wv;

    f32x16 acc = zero16();
#pragma unroll 4
    for (int kk = 0; kk < 128; kk += 16) {
        const float* xp = x + (size_t)(r0 + m) * 128 + kk + kg * 8;
        f32x4 x0 = *(const f32x4*)xp;
        f32x4 x1 = *(const f32x4*)(xp + 4);
        BF8 ah, al;
#pragma unroll
        for (int j = 0; j < 4; j++) {
            u16 hb = f2b_trunc(x0[j]);
            ah.s[j] = hb; al.s[j] = f2b_trunc(x0[j] - b2f(hb));
            u16 hb2 = f2b_trunc(x1[j]);
            ah.s[4 + j] = hb2; al.s[4 + j] = f2b_trunc(x1[j] - b2f(hb2));
        }
        const float* wcol = wp + (size_t)(kk + kg * 8) * 128 + c;
        if (typ < 2) {
            BF8 bh, bl_;
#pragma unroll
            for (int j = 0; j < 8; j++) {
                float w = wcol[(size_t)j * 128];
                u16 hb = f2b_trunc(w);
                bh.s[j] = hb; bl_.s[j] = f2b_trunc(w - b2f(hb));
            }
            acc = __builtin_amdgcn_mfma_f32_32x32x16_bf16(ah.v, bh.v, acc, 0, 0, 0);
            acc = __builtin_amdgcn_mfma_f32_32x32x16_bf16(ah.v, bl_.v, acc, 0, 0, 0);
            acc = __builtin_amdgcn_mfma_f32_32x32x16_bf16(al.v, bh.v, acc, 0, 0, 0);
        } else {
            BF8 bh;
#pragma unroll
            for (int j = 0; j < 8; j++) bh.s[j] = f2b_rne(wcol[(size_t)j * 128]);
            acc = __builtin_amdgcn_mfma_f32_32x32x16_bf16(ah.v, bh.v, acc, 0, 0, 0);
        }
    }

    int b = r0 >> 11, sl = r0 & 2047;
    if (typ < 2) {
        u16* H = typ ? Kph : Qph;
        u16* L = typ ? Kpl : Qpl;
        int hh = c >> 4, d = c & 15;
        if (hh == 7) return;                      // head 7 never consumed
        float scl = (typ == 0) ? SCALE2 : 1.0f;
        size_t hb_off = (size_t)(b * 8 + hh) * 2048 * 16 + d;
#pragma unroll
        for (int r = 0; r < 16; r++) {
            int row = (r & 3) + 8 * (r >> 2) + 4 * kg;
            float v = acc[r] * scl;
            u16 hi = f2b_trunc(v);
            size_t idx = hb_off + (size_t)(sl + row) * 16;
            H[idx] = hi;
            L[idx] = f2b_trunc(v - b2f(hi));
        }
    } else {
        if ((c >> 4) == 7) return;
#pragma unroll
        for (int rg = 0; rg < 4; rg++) {
            int rowb = rg * 8 + 4 * kg;
            BF8 pk;
#pragma unroll
            for (int q = 0; q < 4; q++) pk.s[q] = f2b_rne(acc[rg * 4 + q]);
            u32x4 tmp = pk.q;
            *(u32*)(VT + (size_t)(b * 128 + c) * 2048 + sl + rowb)     = tmp[0];
            *(u32*)(VT + (size_t)(b * 128 + c) * 2048 + sl + rowb + 2) = tmp[1];
        }
    }
}

// ---------------------------------------------------------------------------
// fused attention (R4 numerics + fixes):
//  - S^T orientation (lane = query, keys in regs); bias staged in LDS in
//    MFMA C-layout, fed as the C operand (pass1 approx max, pass2 exact).
//  - pbuf stride 32 u16 (64B rows, everything 16B-aligned) with XOR block
//    swizzle f(r)=(r>>1)&3: reads 8 lanes/4-bank-group (free), writes cover
//    all 32 banks, 4 lanes/2-bank slot (free).  [R6's stride-34 broke
//    alignment -> unaligned-DS splits -> 2x regression]
//  - K prefetch in both passes; 7 blocks/CU resident (grid 1792 = 7x256).
// ---------------------------------------------------------------------------
__global__ __launch_bounds__(256, 7) void attn_kernel(
    const u16* __restrict__ Qph, const u16* __restrict__ Qpl,
    const u16* __restrict__ Kph, const u16* __restrict__ Kpl,
    const u16* __restrict__ VT, const int* __restrict__ mask, u16* AO)
{
    __shared__ char smem[16896];
    u16*   pbuf  = (u16*)smem;               // [4][32][32] u16 = 8192 B (swizzled)
    float* biasC = (float*)(smem + 8192);    // [64 tiles][2 kg][16 reg] = 8192 B
    float* lsmax = (float*)(smem + 16384);   // [32][4] = 512 B
    float* obuf  = (float*)smem;             // [4][16][32] f32, aliases pbuf
    float* lbuf  = (float*)(smem + 8192);    // [4][32] f32, aliases biasC (dead)

    int bid = blockIdx.x;
    int bh = bid % 28;
    int qt = bid / 28;
    int b = bh / 7, h = bh % 7;
    int wave = threadIdx.x >> 6, lane = threadIdx.x & 63;
    int m = lane & 31, kg = lane >> 5;
    int qs = qt * 32;

    // ---- bias table in MFMA C-layout: entry e=(tile*32+kg*16+r)
    //      -> key tile*32 + (r&3)+8*(r>>2)+4*kg ----
    {
        int e0 = threadIdx.x * 8;
        const int* mp = mask + b * 2048;
        float v[8];
#pragma unroll
        for (int j = 0; j < 8; j++) {
            int e = e0 + j;
            int ti = e >> 5, kgg = (e >> 4) & 1, r = e & 15;
            int key = ti * 32 + (r & 3) + 8 * (r >> 2) + 4 * kgg;
            v[j] = (mp[key] != 0) ? 0.0f : MBIAS2;
        }
        *(f32x4*)(biasC + e0)     = *(const f32x4*)&v[0];
        *(f32x4*)(biasC + e0 + 4) = *(const f32x4*)&v[4];
    }
    __syncthreads();

    size_t headoff = (size_t)(b * 8 + h) * 2048 * 16;
    bf16x8 qfh = ld_bf8(Qph + headoff + (size_t)(qs + m) * 16 + kg * 8);
    bf16x8 qfl = ld_bf8(Qpl + headoff + (size_t)(qs + m) * 16 + kg * 8);
    const u16* kbh = Kph + headoff;
    const u16* kbl = Kpl + headoff;

    int t0 = wave * 512;

    // ---- pass 1: per-query max of approx biased scores (K hi x Q hi + bias) ----
    float mloc = -3.0e38f;
    {
        bf16x8 khc = ld_bf8(kbh + (size_t)(t0 + m) * 16 + kg * 8);
        for (int t = t0; t < t0 + 512; t += 32) {
            int tn = (t + 32 < t0 + 512) ? (t + 32) : t0;
            bf16x8 khn = ld_bf8(kbh + (size_t)(tn + m) * 16 + kg * 8);
            f32x16 ci = *(const f32x16*)(biasC + (t >> 5) * 32 + kg * 16);
            f32x16 sc = __builtin_amdgcn_mfma_f32_32x32x16_bf16(khc, qfh, ci, 0, 0, 0);
#pragma unroll
            for (int r = 0; r < 16; r++) mloc = fmaxf(mloc, sc[r]);
            khc = khn;
        }
    }
    mloc = fmaxf(mloc, __shfl_xor(mloc, 32, 64));
    if (kg == 0) lsmax[m * 4 + wave] = mloc;
    __syncthreads();
    f32x4 mv = *(const f32x4*)(lsmax + m * 4);
    float mrow = fmaxf(fmaxf(mv[0], mv[1]), fmaxf(mv[2], mv[3]));  // per-lane (query m)

    // ---- pass 2: exact biased scores -> exp2 -> swizzled P tile -> PV + ones ----
    f32x4 o0 = zero4(), o1 = zero4(), l0 = zero4(), l1 = zero4();
    BF8 onesu;
#pragma unroll
    for (int j = 0; j < 8; j++) onesu.s[j] = 0x3F80;
    bf16x8 ones = onesu.v;

    int q16 = lane & 15, krow = lane >> 4;
    const u16* vtb = VT + (size_t)(b * 128 + h * 16 + q16) * 2048;
    int msw = (m >> 1) & 3;                                  // write swizzle
    int qsw = (q16 >> 1) & 3;                                // read swizzle
    u16* pwb = pbuf + wave * 1024 + m * 32 + kg * 4;
    const u16* pr0 = pbuf + wave * 1024 + q16 * 32 + ((krow ^ qsw) * 8);
    const u16* pr1 = pr0 + 16 * 32;

    bf16x8 khc = ld_bf8(kbh + (size_t)(t0 + m) * 16 + kg * 8);
    bf16x8 klc = ld_bf8(kbl + (size_t)(t0 + m) * 16 + kg * 8);

    for (int t = t0; t < t0 + 512; t += 32) {
        int tn = (t + 32 < t0 + 512) ? (t + 32) : t0;
        bf16x8 khn = ld_bf8(kbh + (size_t)(tn + m) * 16 + kg * 8);
        bf16x8 kln = ld_bf8(kbl + (size_t)(tn + m) * 16 + kg * 8);
        bf16x8 vf  = ld_bf8(vtb + t + krow * 8);

        f32x16 sc = *(const f32x16*)(biasC + (t >> 5) * 32 + kg * 16);
        sc = __builtin_amdgcn_mfma_f32_32x32x16_bf16(khc, qfl, sc, 0, 0, 0);
        sc = __builtin_amdgcn_mfma_f32_32x32x16_bf16(klc, qfh, sc, 0, 0, 0);
        sc = __builtin_amdgcn_mfma_f32_32x32x16_bf16(khc, qfh, sc, 0, 0, 0);
#pragma unroll
        for (int rg = 0; rg < 4; rg++) {
            float e0 = __builtin_amdgcn_exp2f(sc[rg * 4 + 0] - mrow);
            float e1 = __builtin_amdgcn_exp2f(sc[rg * 4 + 1] - mrow);
            float e2 = __builtin_amdgcn_exp2f(sc[rg * 4 + 2] - mrow);
            float e3 = __builtin_amdgcn_exp2f(sc[rg * 4 + 3] - mrow);
            u32x2 pk;
            pk[0] = __builtin_amdgcn_perm(__builtin_bit_cast(u32, e1),
                                          __builtin_bit_cast(u32, e0), 0x07060302u);
            pk[1] = __builtin_amdgcn_perm(__builtin_bit_cast(u32, e3),
                                          __builtin_bit_cast(u32, e2), 0x07060302u);
            *(u32x2*)(pwb + ((rg ^ msw) * 8)) = pk;   // keys rg*8+4kg..+3, query m
        }
        bf16x8 p0 = *(const bf16x8*)pr0;
        bf16x8 p1 = *(const bf16x8*)pr1;
        o0 = __builtin_amdgcn_mfma_f32_16x16x32_bf16(p0, vf, o0, 0, 0, 0);
        o1 = __builtin_amdgcn_mfma_f32_16x16x32_bf16(p1, vf, o1, 0, 0, 0);
        l0 = __builtin_amdgcn_mfma_f32_16x16x32_bf16(p0, ones, l0, 0, 0, 0);
        l1 = __builtin_amdgcn_mfma_f32_16x16x32_bf16(p1, ones, l1, 0, 0, 0);
        khc = khn; klc = kln;
    }

    __syncthreads();     // all P-tile reads done before obuf/lbuf alias writes

    *(f32x4*)(obuf + wave * 512 + q16 * 32 + krow * 4)      = o0;
    *(f32x4*)(obuf + wave * 512 + q16 * 32 + krow * 4 + 16) = o1;
    if (q16 == 0) {
        *(f32x4*)(lbuf + wave * 32 + krow * 4)      = l0;
        *(f32x4*)(lbuf + wave * 32 + krow * 4 + 16) = l1;
    }
    __syncthreads();

    int dd = threadIdx.x & 15, q = threadIdx.x >> 4;
    int slot0 = (h == 0) ? 0 : h + 1;
#pragma unroll
    for (int hf = 0; hf < 2; hf++) {
        int qq = q + hf * 16;
        float os = obuf[0 * 512 + dd * 32 + qq] + obuf[1 * 512 + dd * 32 + qq]
                 + obuf[2 * 512 + dd * 32 + qq] + obuf[3 * 512 + dd * 32 + qq];
        float ls = lbuf[0 * 32 + qq] + lbuf[1 * 32 + qq]
                 + lbuf[2 * 32 + qq] + lbuf[3 * 32 + qq];
        u16 vb = f2b_rne(os * __builtin_amdgcn_rcpf(ls));
        int orow = b * 2048 + qs + qq;
        AO[orow * 128 + slot0 * 16 + dd] = vb;
        if (h == 1) AO[orow * 128 + 16 + dd] = vb;
    }
}

// ---------------------------------------------------------------------------
// final linear: out = AO(bf16) @ lin_w^T + lin_b (lin_w converted in-reg).
// ---------------------------------------------------------------------------
__global__ __launch_bounds__(256) void fin_kernel(
    const u16* __restrict__ AO, const float* __restrict__ lw,
    const float* __restrict__ lb, float* out)
{
    int ct   = threadIdx.x >> 6;
    int lane = threadIdx.x & 63;
    int m = lane & 31, kg = lane >> 5;
    int r0 = blockIdx.x * 32;
    int c = ct * 32 + m;

    f32x16 acc = zero16();
#pragma unroll 4
    for (int kk = 0; kk < 128; kk += 16) {
        bf16x8 af = ld_bf8(AO + (size_t)(r0 + m) * 128 + kk + kg * 8);
        const float* wp = lw + (size_t)c * 128 + kk + kg * 8;
        f32x4 w0 = *(const f32x4*)wp;
        f32x4 w1 = *(const f32x4*)(wp + 4);
        BF8 bfr;
#pragma unroll
        for (int j = 0; j < 4; j++) {
            bfr.s[j]     = f2b_rne(w0[j]);
            bfr.s[4 + j] = f2b_rne(w1[j]);
        }
        acc = __builtin_amdgcn_mfma_f32_32x32x16_bf16(af, bfr.v, acc, 0, 0, 0);
    }
    float bias = lb[c];
#pragma unroll
    for (int r = 0; r < 16; r++) {
        int row = (r & 3) + 8 * (r >> 2) + 4 * kg;
        out[(size_t)(r0 + row) * 128 + c] = acc[r] + bias;
    }
}

// ---------------------------------------------------------------------------
extern "C" void kernel_launch(void* const* d_in, const int* in_sizes, int n_in,
                              void* d_out, int out_size, void* d_ws, size_t ws_size,
                              hipStream_t stream)
{
    const float* x    = (const float*)d_in[0];
    const int*   mask = (const int*)d_in[1];
    const float* wq   = (const float*)d_in[2];
    const float* wk   = (const float*)d_in[3];
    const float* wv   = (const float*)d_in[4];
    const float* lw   = (const float*)d_in[5];
    const float* lb   = (const float*)d_in[6];
    float* out = (float*)d_out;

    char* ws = (char*)d_ws;
    u16* Qph = (u16*)(ws + 0 * 2097152);
    u16* Qpl = (u16*)(ws + 1 * 2097152);
    u16* Kph = (u16*)(ws + 2 * 2097152);
    u16* Kpl = (u16*)(ws + 3 * 2097152);
    u16* VT  = (u16*)(ws + 4 * 2097152);
    u16* AO  = (u16*)(ws + 5 * 2097152);

    proj_kernel<<<dim3(256, 3), 256, 0, stream>>>(x, wq, wk, wv,
                                                  Qph, Qpl, Kph, Kpl, VT);
    attn_kernel<<<1792, 256, 0, stream>>>(Qph, Qpl, Kph, Kpl, VT, mask, AO);
    fin_kernel<<<256, 256, 0, stream>>>(AO, lw, lb, out);
}